// Round 1
// baseline (8819.224 us; speedup 1.0000x reference)
//
#include <hip/hip_runtime.h>
#include <math.h>

constexpr int H    = 500;
constexpr int H3   = 1500;
constexpr int SEQ  = 256;
constexpr int V    = 50257;
constexpr int TDEC = 64;
constexpr int NLB  = (V + 63) / 64;   // logits blocks: 64 rows per block

__device__ __forceinline__ float sigmoidf_(float x) { return 1.f / (1.f + expf(-x)); }

__device__ __forceinline__ float wred(float v) {
  #pragma unroll
  for (int off = 32; off > 0; off >>= 1) v += __shfl_down(v, off, 64);
  return v;
}

// ---------------- init: zero initial hiddens, tok = SOS ----------------
__global__ void init_k(float* f0A, float* b0A, float* f1A, float* b1A, int* tok) {
  int i = blockIdx.x * blockDim.x + threadIdx.x;
  if (i < H) { f0A[i] = 0.f; b0A[i] = 0.f; f1A[i] = 0.f; b1A[i] = 0.f; }
  if (i == 0) tok[0] = 1;  // SOS
}

// ---------------- embedding lookup: ex[t] = emb[seq[t]] ----------------
__global__ void embed_k(const int* __restrict__ seq, const float* __restrict__ emb,
                        float* __restrict__ ex) {
  int t = blockIdx.x;
  int tok = seq[t];
  for (int i = threadIdx.x; i < H; i += blockDim.x)
    ex[(size_t)t * H + i] = emb[(size_t)tok * H + i];
}

// ---------------- C[m][n] = bias[n] + sum_k X[m*K+k] * W[n*K+k] ----------------
__global__ __launch_bounds__(256) void gemm_nt(const float* __restrict__ X,
                                               const float* __restrict__ W,
                                               const float* __restrict__ bias,
                                               float* __restrict__ C,
                                               int M, int N, int K) {
  __shared__ float Xs[64][17];
  __shared__ float Ws[64][17];
  int bm = blockIdx.y * 64, bn = blockIdx.x * 64;
  int tid = threadIdx.x;
  int tx = tid % 16, ty = tid / 16;
  float acc[4][4] = {};
  for (int k0 = 0; k0 < K; k0 += 16) {
    for (int i = tid; i < 64 * 16; i += 256) {
      int m = i / 16, k = i % 16;
      int gm = bm + m, gk = k0 + k, gn = bn + m;
      Xs[m][k] = (gm < M && gk < K) ? X[(size_t)gm * K + gk] : 0.f;
      Ws[m][k] = (gn < N && gk < K) ? W[(size_t)gn * K + gk] : 0.f;
    }
    __syncthreads();
    #pragma unroll
    for (int k = 0; k < 16; ++k) {
      float xv[4], wv[4];
      #pragma unroll
      for (int i = 0; i < 4; ++i) xv[i] = Xs[ty * 4 + i][k];
      #pragma unroll
      for (int j = 0; j < 4; ++j) wv[j] = Ws[tx * 4 + j][k];
      #pragma unroll
      for (int i = 0; i < 4; ++i)
        #pragma unroll
        for (int j = 0; j < 4; ++j) acc[i][j] += xv[i] * wv[j];
    }
    __syncthreads();
  }
  for (int i = 0; i < 4; ++i) {
    int gm = bm + ty * 4 + i;
    if (gm >= M) continue;
    for (int j = 0; j < 4; ++j) {
      int gn = bn + tx * 4 + j;
      if (gn >= N) continue;
      C[(size_t)gm * N + gn] = acc[i][j] + bias[gn];
    }
  }
}

// ---------------- one GRU scan step, fwd (y=0) + bwd (y=1) ----------------
__global__ __launch_bounds__(1024) void gru_scan_step(
    const float* __restrict__ gxF, const float* __restrict__ gxB,
    const float* __restrict__ WhhF, const float* __restrict__ WhhB,
    const float* __restrict__ bhhF, const float* __restrict__ bhhB,
    const float* __restrict__ hFin, float* __restrict__ hFout,
    const float* __restrict__ hBin, float* __restrict__ hBout,
    float* __restrict__ yF, float* __restrict__ yB,
    int ystride, int t) {
  int dir = blockIdx.y;
  const float *gx, *Whh, *bhh, *hin;
  float *hout, *y;
  int teff;
  if (dir == 0) { gx = gxF; Whh = WhhF; bhh = bhhF; hin = hFin; hout = hFout; y = yF; teff = t; }
  else          { gx = gxB; Whh = WhhB; bhh = bhhB; hin = hBin; hout = hBout; y = yB; teff = SEQ - 1 - t; }
  int wid = threadIdx.x >> 6, lane = threadIdx.x & 63;
  int i = blockIdx.x * 16 + wid;
  if (i >= H) return;
  const float* wr = Whh + (size_t)i * H;
  const float* wz = Whh + (size_t)(H + i) * H;
  const float* wn = Whh + (size_t)(2 * H + i) * H;
  float sr = 0.f, sz = 0.f, sn = 0.f;
  for (int k = lane; k < H; k += 64) {
    float hk = hin[k];
    sr += wr[k] * hk; sz += wz[k] * hk; sn += wn[k] * hk;
  }
  sr = wred(sr); sz = wred(sz); sn = wred(sn);
  if (lane == 0) {
    const float* g = gx + (size_t)teff * H3;
    float rh = sr + bhh[i], zh = sz + bhh[H + i], nh = sn + bhh[2 * H + i];
    float r = sigmoidf_(g[i] + rh);
    float z = sigmoidf_(g[H + i] + zh);
    float n = tanhf(g[2 * H + i] + r * nh);
    float hp = (1.f - z) * n + z * hin[i];
    hout[i] = hp;
    y[(size_t)teff * ystride + i] = hp;
  }
}

// ---------------- enc_out = y1f + y1b ----------------
__global__ void add_k(const float* __restrict__ a, const float* __restrict__ b,
                      float* __restrict__ c, int n) {
  int i = blockIdx.x * blockDim.x + threadIdx.x;
  if (i < n) c[i] = a[i] + b[i];
}

// ---------------- decoder GRU cell ----------------
__global__ __launch_bounds__(1024) void dec_cell(
    const int* __restrict__ tok, const float* __restrict__ emb,
    const float* __restrict__ xbuf,
    const float* __restrict__ hin, float* __restrict__ hout,
    const float* __restrict__ Wih, const float* __restrict__ Whh,
    const float* __restrict__ bih, const float* __restrict__ bhh) {
  const float* x = xbuf ? xbuf : (emb + (size_t)tok[0] * H);
  int wid = threadIdx.x >> 6, lane = threadIdx.x & 63;
  int i = blockIdx.x * 16 + wid;
  if (i >= H) return;
  const float* wir = Wih + (size_t)i * H;
  const float* wiz = Wih + (size_t)(H + i) * H;
  const float* win = Wih + (size_t)(2 * H + i) * H;
  const float* whr = Whh + (size_t)i * H;
  const float* whz = Whh + (size_t)(H + i) * H;
  const float* whn = Whh + (size_t)(2 * H + i) * H;
  float sxr = 0.f, sxz = 0.f, sxn = 0.f, shr = 0.f, shz = 0.f, shn = 0.f;
  for (int k = lane; k < H; k += 64) {
    float xk = x[k], hk = hin[k];
    sxr += wir[k] * xk; sxz += wiz[k] * xk; sxn += win[k] * xk;
    shr += whr[k] * hk; shz += whz[k] * hk; shn += whn[k] * hk;
  }
  sxr = wred(sxr); sxz = wred(sxz); sxn = wred(sxn);
  shr = wred(shr); shz = wred(shz); shn = wred(shn);
  if (lane == 0) {
    float r = sigmoidf_(sxr + bih[i] + shr + bhh[i]);
    float z = sigmoidf_(sxz + bih[H + i] + shz + bhh[H + i]);
    float n = tanhf(sxn + bih[2 * H + i] + r * (shn + bhh[2 * H + i]));
    hout[i] = (1.f - z) * n + z * hin[i];
  }
}

// ---------------- attention scores[s] = dot(enc_out[s], rnn) ----------------
__global__ __launch_bounds__(1024) void attn_scores(const float* __restrict__ enc_out,
                                                    const float* __restrict__ rnn,
                                                    float* __restrict__ scores) {
  int wid = threadIdx.x >> 6, lane = threadIdx.x & 63;
  int s = blockIdx.x * 16 + wid;
  if (s >= SEQ) return;
  const float* row = enc_out + (size_t)s * H;
  float acc = 0.f;
  for (int k = lane; k < H; k += 64) acc += row[k] * rnn[k];
  acc = wred(acc);
  if (lane == 0) scores[s] = acc;
}

// ---------------- softmax(scores) then ctx = w @ enc_out ----------------
__global__ __launch_bounds__(256) void attn_ctx(const float* __restrict__ scores,
                                                const float* __restrict__ enc_out,
                                                float* __restrict__ ctx) {
  __shared__ float w[SEQ];
  __shared__ float red[256];
  int tid = threadIdx.x;
  float v = scores[tid];  // SEQ == 256 == blockDim
  red[tid] = v; __syncthreads();
  for (int s = 128; s > 0; s >>= 1) {
    if (tid < s) red[tid] = fmaxf(red[tid], red[tid + s]);
    __syncthreads();
  }
  float m = red[0]; __syncthreads();
  float e = expf(v - m);
  red[tid] = e; __syncthreads();
  for (int s = 128; s > 0; s >>= 1) {
    if (tid < s) red[tid] += red[tid + s];
    __syncthreads();
  }
  float inv = 1.f / red[0]; __syncthreads();
  w[tid] = e * inv; __syncthreads();
  int j = blockIdx.x * 256 + tid;
  if (j < H) {
    float acc = 0.f;
    for (int s = 0; s < SEQ; ++s) acc += w[s] * enc_out[(size_t)s * H + j];
    ctx[j] = acc;
  }
}

// ---------------- c = tanh(concat_W @ [rnn; ctx] + concat_b) ----------------
__global__ __launch_bounds__(1024) void concat_c(const float* __restrict__ CW,
                                                 const float* __restrict__ cb,
                                                 const float* __restrict__ rnn,
                                                 const float* __restrict__ ctx,
                                                 float* __restrict__ cvec) {
  int wid = threadIdx.x >> 6, lane = threadIdx.x & 63;
  int i = blockIdx.x * 16 + wid;
  if (i >= H) return;
  const float* row = CW + (size_t)i * (2 * H);
  float acc = 0.f;
  for (int k = lane; k < 2 * H; k += 64) {
    float xv = (k < H) ? rnn[k] : ctx[k - H];
    acc += row[k] * xv;
  }
  acc = wred(acc);
  if (lane == 0) cvec[i] = tanhf(acc + cb[i]);
}

// ---------------- logits = out_W @ c + out_b, with per-block max/argmax ----------------
__global__ __launch_bounds__(1024) void logits_k(const float* __restrict__ outW,
                                                 const float* __restrict__ outb,
                                                 const float* __restrict__ cvec,
                                                 float* __restrict__ logits,
                                                 float* __restrict__ pmax,
                                                 int* __restrict__ pidx) {
  __shared__ float c_s[H];
  __shared__ float lmax[16];
  __shared__ int   lidx[16];
  for (int k = threadIdx.x; k < H; k += 1024) c_s[k] = cvec[k];
  __syncthreads();
  int wid = threadIdx.x >> 6, lane = threadIdx.x & 63;
  int gw = blockIdx.x * 16 + wid;
  float bm = -INFINITY; int bi = V;
  #pragma unroll
  for (int rr = 0; rr < 4; ++rr) {
    int row = gw * 4 + rr;
    if (row < V) {
      const float* wrow = outW + (size_t)row * H;
      float acc = 0.f;
      for (int k = lane; k < H; k += 64) acc += wrow[k] * c_s[k];
      acc = wred(acc);
      if (lane == 0) {
        float l = acc + outb[row];
        logits[row] = l;
        if (l > bm) { bm = l; bi = row; }
      }
    }
  }
  if (lane == 0) { lmax[wid] = bm; lidx[wid] = bi; }
  __syncthreads();
  if (threadIdx.x == 0) {
    float m = -INFINITY; int ix = V;
    for (int wq = 0; wq < 16; ++wq) {
      if (lmax[wq] > m || (lmax[wq] == m && lidx[wq] < ix)) { m = lmax[wq]; ix = lidx[wq]; }
    }
    pmax[blockIdx.x] = m; pidx[blockIdx.x] = ix;
  }
}

// ---------------- global argmax + softmax + write outputs ----------------
__global__ __launch_bounds__(1024) void finalize_k(const float* __restrict__ pmax,
                                                   const int* __restrict__ pidx, int nblk,
                                                   float* __restrict__ logits,
                                                   int* __restrict__ tok,
                                                   float* __restrict__ out_tokens,
                                                   float* __restrict__ out_probs, int step) {
  __shared__ float rm[1024];
  __shared__ int   ri[1024];
  int tid = threadIdx.x;
  float m = -INFINITY; int ix = V;
  for (int b = tid; b < nblk; b += 1024) {
    float v = pmax[b]; int id = pidx[b];
    if (v > m || (v == m && id < ix)) { m = v; ix = id; }
  }
  rm[tid] = m; ri[tid] = ix; __syncthreads();
  for (int s = 512; s > 0; s >>= 1) {
    if (tid < s) {
      if (rm[tid + s] > rm[tid] || (rm[tid + s] == rm[tid] && ri[tid + s] < ri[tid])) {
        rm[tid] = rm[tid + s]; ri[tid] = ri[tid + s];
      }
    }
    __syncthreads();
  }
  float gmax = rm[0]; int gidx = ri[0];
  __syncthreads();
  if (tid == 0) { tok[0] = gidx; out_tokens[step] = (float)gidx; }
  float sum = 0.f;
  for (int v = tid; v < V; v += 1024) {
    float e = expf(logits[v] - gmax);
    logits[v] = e;
    sum += e;
  }
  rm[tid] = sum; __syncthreads();
  for (int s = 512; s > 0; s >>= 1) {
    if (tid < s) rm[tid] += rm[tid + s];
    __syncthreads();
  }
  float inv = 1.f / rm[0];
  for (int v = tid; v < V; v += 1024)
    out_probs[(size_t)step * V + v] = logits[v] * inv;
}

extern "C" void kernel_launch(void* const* d_in, const int* in_sizes, int n_in,
                              void* d_out, int out_size, void* d_ws, size_t ws_size,
                              hipStream_t stream) {
  const int*   seq   = (const int*)d_in[0];
  const float* emb   = (const float*)d_in[3];
  const float* e0f_Wih = (const float*)d_in[4];
  const float* e0f_Whh = (const float*)d_in[5];
  const float* e0f_bih = (const float*)d_in[6];
  const float* e0f_bhh = (const float*)d_in[7];
  const float* e0b_Wih = (const float*)d_in[8];
  const float* e0b_Whh = (const float*)d_in[9];
  const float* e0b_bih = (const float*)d_in[10];
  const float* e0b_bhh = (const float*)d_in[11];
  const float* e1f_Wih = (const float*)d_in[12];
  const float* e1f_Whh = (const float*)d_in[13];
  const float* e1f_bih = (const float*)d_in[14];
  const float* e1f_bhh = (const float*)d_in[15];
  const float* e1b_Wih = (const float*)d_in[16];
  const float* e1b_Whh = (const float*)d_in[17];
  const float* e1b_bih = (const float*)d_in[18];
  const float* e1b_bhh = (const float*)d_in[19];
  const float* dWih = (const float*)d_in[20];
  const float* dWhh = (const float*)d_in[21];
  const float* dbih = (const float*)d_in[22];
  const float* dbhh = (const float*)d_in[23];
  const float* cW   = (const float*)d_in[24];
  const float* cb   = (const float*)d_in[25];
  const float* outW = (const float*)d_in[26];
  const float* outb = (const float*)d_in[27];

  float* w = (float*)d_ws;
  float* ex      = w;                    // 128000
  float* x1      = ex + 128000;          // 256000
  float* gxf     = x1 + 256000;          // 384000
  float* gxb     = gxf + 384000;         // 384000
  float* y1f     = gxb + 384000;         // 128000
  float* y1b     = y1f + 128000;         // 128000
  float* enc_out = y1b + 128000;         // 128000
  float* f0A = enc_out + 128000;
  float* f0B = f0A + 512;
  float* b0A = f0B + 512;
  float* b0B = b0A + 512;
  float* f1A = b0B + 512;
  float* f1B = f1A + 512;
  float* b1A = f1B + 512;
  float* b1B = b1A + 512;
  float* dh0B = b1B + 512;
  float* dh1B = dh0B + 512;
  float* scores = dh1B + 512;            // 512
  float* ctx    = scores + 512;          // 512
  float* cvec   = ctx + 512;             // 512
  float* logits = cvec + 512;            // 50432
  float* pmax   = logits + 50432;        // 1024
  int*   pidx   = (int*)(pmax + 1024);   // 1024 ints
  int*   tokp   = pidx + 1024;

  float* outf = (float*)d_out;

  init_k<<<2, 256, 0, stream>>>(f0A, b0A, f1A, b1A, tokp);
  embed_k<<<SEQ, 128, 0, stream>>>(seq, emb, ex);

  // encoder layer 0
  gemm_nt<<<dim3(24, 4), 256, 0, stream>>>(ex, e0f_Wih, e0f_bih, gxf, SEQ, H3, H);
  gemm_nt<<<dim3(24, 4), 256, 0, stream>>>(ex, e0b_Wih, e0b_bih, gxb, SEQ, H3, H);
  for (int t = 0; t < SEQ; ++t) {
    float* hfi = (t & 1) ? f0B : f0A;
    float* hfo = (t & 1) ? f0A : f0B;
    float* hbi = (t & 1) ? b0B : b0A;
    float* hbo = (t & 1) ? b0A : b0B;
    gru_scan_step<<<dim3(32, 2), 1024, 0, stream>>>(gxf, gxb, e0f_Whh, e0b_Whh,
        e0f_bhh, e0b_bhh, hfi, hfo, hbi, hbo, x1, x1 + H, 2 * H, t);
  }

  // encoder layer 1
  gemm_nt<<<dim3(24, 4), 256, 0, stream>>>(x1, e1f_Wih, e1f_bih, gxf, SEQ, H3, 2 * H);
  gemm_nt<<<dim3(24, 4), 256, 0, stream>>>(x1, e1b_Wih, e1b_bih, gxb, SEQ, H3, 2 * H);
  for (int t = 0; t < SEQ; ++t) {
    float* hfi = (t & 1) ? f1B : f1A;
    float* hfo = (t & 1) ? f1A : f1B;
    float* hbi = (t & 1) ? b1B : b1A;
    float* hbo = (t & 1) ? b1A : b1B;
    gru_scan_step<<<dim3(32, 2), 1024, 0, stream>>>(gxf, gxb, e1f_Whh, e1b_Whh,
        e1f_bhh, e1b_bhh, hfi, hfo, hbi, hbo, y1f, y1b, H, t);
  }
  add_k<<<(SEQ * H + 255) / 256, 256, 0, stream>>>(y1f, y1b, enc_out, SEQ * H);

  // decoder
  for (int st = 0; st < TDEC; ++st) {
    float* h0i = (st & 1) ? dh0B : f0A;
    float* h0o = (st & 1) ? f0A : dh0B;
    float* h1i = (st & 1) ? dh1B : b0A;
    float* h1o = (st & 1) ? b0A : dh1B;
    dec_cell<<<32, 1024, 0, stream>>>(tokp, emb, nullptr, h0i, h0o,
        dWih, dWhh, dbih, dbhh);
    dec_cell<<<32, 1024, 0, stream>>>(tokp, emb, h0o, h1i, h1o,
        dWih + (size_t)H3 * H, dWhh + (size_t)H3 * H, dbih + H3, dbhh + H3);
    attn_scores<<<16, 1024, 0, stream>>>(enc_out, h1o, scores);
    attn_ctx<<<2, 256, 0, stream>>>(scores, enc_out, ctx);
    concat_c<<<32, 1024, 0, stream>>>(cW, cb, h1o, ctx, cvec);
    logits_k<<<NLB, 1024, 0, stream>>>(outW, outb, cvec, logits, pmax, pidx);
    finalize_k<<<1, 1024, 0, stream>>>(pmax, pidx, NLB, logits, tokp,
        outf, outf + TDEC, st);
  }
}